// Round 1
// baseline (12658.282 us; speedup 1.0000x reference)
//
#include <hip/hip_runtime.h>

// MACRO_VRNN: 63-step scan, partitioned as (agent, batch-chunk-of-8) x 320 wgs,
// one kernel launch per step. f32 throughout. h_mac GRU replicated per agent and
// deferred to start of next step so each step is internally sync-free.

#define T_STEPS 63
#define BATCH   512
#define NA      5
#define YDIM    10
#define ZDIM    16
#define XDIM    2
#define HD      200
#define MDIM    90
#define HM      200
#define NB      8
#define NT      256

struct Params {
  const float *yin;
  const int   *mg;
  const float *Wdm1,*bdm1,*Wdm2,*bdm2;
  const float *Wpr1,*bpr1,*Wpr2,*bpr2,*Wpm,*bpm,*Wps,*bps;
  const float *Wd1,*bd1,*Wd2,*bd2,*Wdx,*bdx,*Wds,*bds;
  const float *bih_mic,*bhh_mic,*bih_mac,*bhh_mac;
  const float *eps_g,*eps_z,*eps_x;
  const int   *burn;
  const float *WihTmic,*WhhTmic,*WihTmac,*WhhTmac;
  float *hmac_ws,*hmic_ws;
  int   *idxA,*idxB;
  float *ret,*goals;
};

__device__ __forceinline__ float sigm(float x){ return 1.f/(1.f+expf(-x)); }
__device__ __forceinline__ float softplusf(float x){ return log1pf(expf(-fabsf(x))) + fmaxf(x,0.f); }

// acc[j] += sum_k act[j*stride+k] * W[k*N+o]
template<int NBv>
__device__ __forceinline__ void mv(const float* __restrict__ W, int N, int K,
                                   const float* __restrict__ act, int stride,
                                   int o, float* __restrict__ acc)
{
  const int K4 = K >> 2;
  const float* wp = W + o;
  for (int q = 0; q < K4; ++q) {
    const float w0 = wp[0];
    const float w1 = wp[N];
    const float w2 = wp[2*N];
    const float w3 = wp[3*N];
    wp += 4*N;
    const float* ap = act + 4*q;
    #pragma unroll
    for (int j = 0; j < NBv; ++j) {
      const float4 av = *reinterpret_cast<const float4*>(ap + j*stride);
      acc[j] = fmaf(av.x, w0, acc[j]);
      acc[j] = fmaf(av.y, w1, acc[j]);
      acc[j] = fmaf(av.z, w2, acc[j]);
      acc[j] = fmaf(av.w, w3, acc[j]);
    }
  }
  for (int k = K4*4; k < K; ++k) {
    const float wv = wp[0];
    wp += N;
    #pragma unroll
    for (int j = 0; j < NBv; ++j)
      acc[j] = fmaf(act[j*stride + k], wv, acc[j]);
  }
}

__global__ void prep_kernel(const float* __restrict__ Whh_mac, const float* __restrict__ Whh_mic,
                            const float* __restrict__ Wih_mic, const float* __restrict__ Wih_mac,
                            float* __restrict__ WhhTmac, float* __restrict__ WhhTmic,
                            float* __restrict__ WihTmic, float* __restrict__ WihTmac)
{
  int i = blockIdx.x * 256 + threadIdx.x;
  if (i < 120000) {                     // (600,200)->(200,600)
    int k = i / 600, g = i % 600;
    WhhTmac[i] = Whh_mac[g*200 + k];
  } else if (i < 720000) {              // (A,600,200)->(A,200,600)
    int j = i - 120000;
    int a = j / 120000, r = j % 120000;
    int k = r / 600, g = r % 600;
    WhhTmic[j] = Whh_mic[a*120000 + g*200 + k];
  } else if (i < 774000) {              // (A,600,18)->(A,18,600)
    int j = i - 720000;
    int a = j / 10800, r = j % 10800;
    int k = r / 600, g = r % 600;
    WihTmic[j] = Wih_mic[a*10800 + g*18 + k];
  } else if (i < 1044000) {             // (600,450)->(450,600)
    int j = i - 774000;
    int k = j / 600, g = j % 600;
    WihTmac[j] = Wih_mac[g*450 + k];
  }
}

__global__ __launch_bounds__(NT, 2) void step_kernel(Params p, int t)
{
  __shared__ __align__(16) float sY[NB][12];
  __shared__ __align__(16) float sHmac[NB][208];
  __shared__ __align__(16) float sHmic[NB][208];
  __shared__ __align__(16) float sGS[NB][608];
  __shared__ __align__(16) float sHn[NB][208];
  __shared__ __align__(16) float sB1[NB][208];
  __shared__ __align__(16) float sB2[NB][208];
  __shared__ __align__(16) float sLog[NB][96];
  __shared__ __align__(16) float sZ[NB][16];
  __shared__ __align__(16) float sXC[NB][20];
  __shared__ float sRedM[NB][2][8];
  __shared__ float sRedS[NB][2][8];
  __shared__ int   sIdxP[NA][NB];
  __shared__ int   sMid[NB];

  const int tid = threadIdx.x;
  // XCD-aware swizzle: agent-major order j=a*64+c, chunks of 40 per XCD so each
  // XCD's L2 working set spans at most 2 agents' weights (~4.2MB).
  const int bid = blockIdx.x;
  const int X = bid & 7, slot = bid >> 3;
  const int jj = X * 40 + slot;
  const int a  = jj >> 6;
  const int b0 = (jj & 63) * NB;
  const int burn = p.burn[0];
  const int* idxPrev = (t & 1) ? p.idxA : p.idxB;
  int*       idxCur  = (t & 1) ? p.idxB : p.idxA;

  // ---- P0: load y, h_mac, h_mic, prev idx ----
  for (int u = tid; u < NB*YDIM; u += NT) {
    int j = u / YDIM, k = u % YDIM;
    float yv = (t == 0) ? p.yin[(b0+j)*YDIM + k]
                        : p.ret[(size_t)t*BATCH*YDIM + (b0+j)*YDIM + k];
    sY[j][k] = yv;
  }
  for (int u = tid; u < NB*HM; u += NT) {
    int j = u / HM, k = u % HM;
    size_t soff = ((size_t)a*BATCH + b0 + j)*HM + k;
    sHmac[j][k] = (t <= 1) ? 0.f : p.hmac_ws[soff];
    sHmic[j][k] = (t == 0) ? 0.f : p.hmic_ws[soff];
  }
  if (tid < NA*NB) {
    int a2 = tid / NB, j = tid % NB;
    sIdxP[a2][j] = (t == 0) ? -1 : idxPrev[a2*BATCH + b0 + j];
  }
  if (t == 0 && tid < NB*XDIM) {   // ret[0] = y[0] (each agent writes its 2 dims)
    int j = tid >> 1, o = tid & 1;
    p.ret[(b0+j)*YDIM + a*XDIM + o] = p.yin[(b0+j)*YDIM + a*XDIM + o];
  }
  __syncthreads();

  // ---- P1: h_mac GRU (deferred from previous step), replicated per agent ----
  if (t > 0) {
    for (int g = tid; g < 600; g += NT) {
      float aI[NB], aH[NB];
      const float bi = p.bih_mac[g], bh = p.bhh_mac[g];
      #pragma unroll
      for (int j = 0; j < NB; ++j) { aI[j] = bi; aH[j] = bh; }
      for (int a2 = 0; a2 < NA; ++a2) {
        #pragma unroll
        for (int j = 0; j < NB; ++j) {
          int r = sIdxP[a2][j];
          if (r >= 0) aI[j] += p.WihTmac[(size_t)(a2*MDIM + r)*600 + g];
        }
      }
      mv<NB>(p.WhhTmac, 600, HM, &sHmac[0][0], 208, g, aH);
      if (g < 400) {
        #pragma unroll
        for (int j = 0; j < NB; ++j) sGS[j][g] = aI[j] + aH[j];
      } else {
        #pragma unroll
        for (int j = 0; j < NB; ++j) { sGS[j][g] = aI[j]; sHn[j][g-400] = aH[j]; }
      }
    }
    __syncthreads();
    for (int u = tid; u < NB*HM; u += NT) {
      int j = u / HM, k = u % HM;
      float r  = sigm(sGS[j][k]);
      float zg = sigm(sGS[j][200+k]);
      float nh = (1.f - zg)*tanhf(sGS[j][400+k] + r*sHn[j][k]) + zg*sHmac[j][k];
      sHmac[j][k] = nh;
      p.hmac_ws[((size_t)a*BATCH + b0 + j)*HM + k] = nh;
    }
    __syncthreads();
  }

  // ---- P2: hdm = relu([y,hmac] @ Wdm1), logits = hdm @ Wdm2 ----
  for (int o = tid; o < HD; o += NT) {
    float acc[NB];
    const float bv = p.bdm1[a*HD + o];
    #pragma unroll
    for (int j = 0; j < NB; ++j) acc[j] = bv;
    const float* W = p.Wdm1 + (size_t)a*(YDIM+HM)*HD;
    mv<NB>(W, HD, YDIM, &sY[0][0], 12, o, acc);
    mv<NB>(W + (size_t)YDIM*HD, HD, HM, &sHmac[0][0], 208, o, acc);
    #pragma unroll
    for (int j = 0; j < NB; ++j) sB1[j][o] = fmaxf(acc[j], 0.f);
  }
  __syncthreads();
  for (int o = tid; o < MDIM; o += NT) {
    float acc[NB];
    const float bv = p.bdm2[a*MDIM + o];
    #pragma unroll
    for (int j = 0; j < NB; ++j) acc[j] = bv;
    mv<NB>(p.Wdm2 + (size_t)a*HD*MDIM, MDIM, HD, &sB1[0][0], 208, o, acc);
    #pragma unroll
    for (int j = 0; j < NB; ++j) sLog[j][o] = acc[j];
  }
  __syncthreads();
  // add gumbel noise (log_softmax is a per-row constant shift -> argmax-equivalent)
  for (int u = tid; u < NB*MDIM; u += NT) {
    int j = u / MDIM, cc = u % MDIM;
    sLog[j][cc] += p.eps_g[(((size_t)t*NA + a)*BATCH + b0 + j)*MDIM + cc];
  }
  __syncthreads();
  if (tid < NB) {
    int j = tid;
    float best = sLog[j][0]; int bi = 0;
    for (int cc = 1; cc < MDIM; ++cc) { float v = sLog[j][cc]; if (v > best) { best = v; bi = cc; } }
    int curr = p.mg[(size_t)t*BATCH*NA + a];               // macro_goals[t,0,a]
    bool sf = (curr == -1) || ((t >= burn) && (burn > 0));
    int mi = sf ? bi : ((b0 + j) == 0 ? curr : -1);        // -1 == zero one-hot
    sMid[j] = mi;
    float gv = (float)(mi < 0 ? 0 : mi);
    p.goals[(size_t)t*BATCH*NA + (b0+j)*NA + a] = gv;
    if (t == T_STEPS-1) p.goals[(size_t)T_STEPS*BATCH*NA + (b0+j)*NA + a] = gv;
    idxCur[a*BATCH + b0 + j] = mi;
  }
  __syncthreads();

  // ---- P3: hp = relu(relu([m,hmic]@Wpr1)@Wpr2); z = pm + softplus(ps)*eps_z ----
  for (int o = tid; o < HD; o += NT) {
    float acc[NB];
    const float bv = p.bpr1[a*HD + o];
    #pragma unroll
    for (int j = 0; j < NB; ++j) acc[j] = bv;
    const float* W = p.Wpr1 + (size_t)a*(MDIM+HM)*HD;
    #pragma unroll
    for (int j = 0; j < NB; ++j) { int mi = sMid[j]; if (mi >= 0) acc[j] += W[(size_t)mi*HD + o]; }
    mv<NB>(W + (size_t)MDIM*HD, HD, HM, &sHmic[0][0], 208, o, acc);
    #pragma unroll
    for (int j = 0; j < NB; ++j) sB2[j][o] = fmaxf(acc[j], 0.f);
  }
  __syncthreads();
  for (int o = tid; o < HD; o += NT) {
    float acc[NB];
    const float bv = p.bpr2[a*HD + o];
    #pragma unroll
    for (int j = 0; j < NB; ++j) acc[j] = bv;
    mv<NB>(p.Wpr2 + (size_t)a*HD*HD, HD, HD, &sB2[0][0], 208, o, acc);
    #pragma unroll
    for (int j = 0; j < NB; ++j) sB1[j][o] = fmaxf(acc[j], 0.f);
  }
  __syncthreads();
  if (tid < NB*ZDIM) {       // 128 threads: (j, o)
    int j = tid >> 4, o = tid & 15;
    float am = p.bpm[a*ZDIM + o], as = p.bps[a*ZDIM + o];
    const float* wm  = p.Wpm + (size_t)a*HD*ZDIM + o;
    const float* wsp = p.Wps + (size_t)a*HD*ZDIM + o;
    for (int k = 0; k < HD; ++k) {
      float h = sB1[j][k];
      am = fmaf(h, wm[(size_t)k*ZDIM], am);
      as = fmaf(h, wsp[(size_t)k*ZDIM], as);
    }
    float zv = am + softplusf(as) * p.eps_z[(((size_t)t*NA + a)*BATCH + b0 + j)*ZDIM + o];
    sZ[j][o] = zv;
    sXC[j][2+o] = zv;
  }
  __syncthreads();

  // ---- P4: hd = relu(relu([y,m,z,hmic]@Wd1)@Wd2); x = dx + softplus(ds)*eps_x ----
  for (int o = tid; o < HD; o += NT) {
    float acc[NB];
    const float bv = p.bd1[a*HD + o];
    #pragma unroll
    for (int j = 0; j < NB; ++j) acc[j] = bv;
    const float* W = p.Wd1 + (size_t)a*(YDIM+MDIM+ZDIM+HM)*HD;
    #pragma unroll
    for (int j = 0; j < NB; ++j) { int mi = sMid[j]; if (mi >= 0) acc[j] += W[(size_t)(YDIM+mi)*HD + o]; }
    mv<NB>(W, HD, YDIM, &sY[0][0], 12, o, acc);
    mv<NB>(W + (size_t)(YDIM+MDIM)*HD, HD, ZDIM, &sZ[0][0], 16, o, acc);
    mv<NB>(W + (size_t)(YDIM+MDIM+ZDIM)*HD, HD, HM, &sHmic[0][0], 208, o, acc);
    #pragma unroll
    for (int j = 0; j < NB; ++j) sB2[j][o] = fmaxf(acc[j], 0.f);
  }
  __syncthreads();
  for (int o = tid; o < HD; o += NT) {
    float acc[NB];
    const float bv = p.bd2[a*HD + o];
    #pragma unroll
    for (int j = 0; j < NB; ++j) acc[j] = bv;
    mv<NB>(p.Wd2 + (size_t)a*HD*HD, HD, HD, &sB2[0][0], 208, o, acc);
    #pragma unroll
    for (int j = 0; j < NB; ++j) sB1[j][o] = fmaxf(acc[j], 0.f);
  }
  __syncthreads();
  if (tid < 128) {           // (j, o, kseg): k-split partial sums for the N=2 heads
    int j = tid >> 4, o = (tid >> 3) & 1, seg = tid & 7;
    float am = 0.f, as = 0.f;
    const float* wx  = p.Wdx + (size_t)a*HD*XDIM + o;
    const float* wsd = p.Wds + (size_t)a*HD*XDIM + o;
    for (int k = seg*25; k < seg*25 + 25; ++k) {
      float h = sB1[j][k];
      am = fmaf(h, wx[(size_t)k*XDIM], am);
      as = fmaf(h, wsd[(size_t)k*XDIM], as);
    }
    sRedM[j][o][seg] = am; sRedS[j][o][seg] = as;
  }
  __syncthreads();
  if (tid < NB*XDIM) {
    int j = tid >> 1, o = tid & 1;
    float am = p.bdx[a*XDIM + o], as = p.bds[a*XDIM + o];
    for (int s2 = 0; s2 < 8; ++s2) { am += sRedM[j][o][s2]; as += sRedS[j][o][s2]; }
    float xs = am + softplusf(as) * p.eps_x[(((size_t)t*NA + a)*BATCH + b0 + j)*XDIM + o];
    float xt = p.yin[((size_t)(t+1))*BATCH*YDIM + (b0+j)*YDIM + a*XDIM + o];
    float xv = (t < burn) ? xt : xs;
    p.ret[((size_t)(t+1))*BATCH*YDIM + (b0+j)*YDIM + a*XDIM + o] = xv;
    sXC[j][o] = xv;
  }
  __syncthreads();

  // ---- P5: h_mic GRU ----
  for (int g = tid; g < 600; g += NT) {
    float aI[NB], aH[NB];
    const float bi = p.bih_mic[a*600 + g], bh = p.bhh_mic[a*600 + g];
    #pragma unroll
    for (int j = 0; j < NB; ++j) { aI[j] = bi; aH[j] = bh; }
    mv<NB>(p.WihTmic + (size_t)a*18*600, 600, 18, &sXC[0][0], 20, g, aI);
    mv<NB>(p.WhhTmic + (size_t)a*HM*600, 600, HM, &sHmic[0][0], 208, g, aH);
    if (g < 400) {
      #pragma unroll
      for (int j = 0; j < NB; ++j) sGS[j][g] = aI[j] + aH[j];
    } else {
      #pragma unroll
      for (int j = 0; j < NB; ++j) { sGS[j][g] = aI[j]; sHn[j][g-400] = aH[j]; }
    }
  }
  __syncthreads();
  for (int u = tid; u < NB*HM; u += NT) {
    int j = u / HM, k = u % HM;
    float r  = sigm(sGS[j][k]);
    float zg = sigm(sGS[j][200+k]);
    float nh = (1.f - zg)*tanhf(sGS[j][400+k] + r*sHn[j][k]) + zg*sHmic[j][k];
    p.hmic_ws[((size_t)a*BATCH + b0 + j)*HM + k] = nh;
  }
}

extern "C" void kernel_launch(void* const* d_in, const int* in_sizes, int n_in,
                              void* d_out, int out_size, void* d_ws, size_t ws_size,
                              hipStream_t stream) {
  (void)in_sizes; (void)n_in; (void)out_size; (void)ws_size;
  Params p;
  p.yin   = (const float*)d_in[0];
  p.mg    = (const int*)  d_in[1];
  p.Wdm1  = (const float*)d_in[2];  p.bdm1 = (const float*)d_in[3];
  p.Wdm2  = (const float*)d_in[4];  p.bdm2 = (const float*)d_in[5];
  p.Wpr1  = (const float*)d_in[6];  p.bpr1 = (const float*)d_in[7];
  p.Wpr2  = (const float*)d_in[8];  p.bpr2 = (const float*)d_in[9];
  p.Wpm   = (const float*)d_in[10]; p.bpm  = (const float*)d_in[11];
  p.Wps   = (const float*)d_in[12]; p.bps  = (const float*)d_in[13];
  p.Wd1   = (const float*)d_in[14]; p.bd1  = (const float*)d_in[15];
  p.Wd2   = (const float*)d_in[16]; p.bd2  = (const float*)d_in[17];
  p.Wdx   = (const float*)d_in[18]; p.bdx  = (const float*)d_in[19];
  p.Wds   = (const float*)d_in[20]; p.bds  = (const float*)d_in[21];
  const float* Wih_mic = (const float*)d_in[22];
  const float* Whh_mic = (const float*)d_in[23];
  p.bih_mic = (const float*)d_in[24]; p.bhh_mic = (const float*)d_in[25];
  const float* Wih_mac = (const float*)d_in[26];
  const float* Whh_mac = (const float*)d_in[27];
  p.bih_mac = (const float*)d_in[28]; p.bhh_mac = (const float*)d_in[29];
  p.eps_g = (const float*)d_in[30];
  p.eps_z = (const float*)d_in[31];
  p.eps_x = (const float*)d_in[32];
  p.burn  = (const int*)  d_in[33];

  float* ws = (float*)d_ws;
  float* WhhTmac = ws;               // 120000
  float* WhhTmic = ws + 120000;      // 600000
  float* WihTmic = ws + 720000;      // 54000
  float* WihTmac = ws + 774000;      // 270000
  p.hmac_ws = ws + 1044000;          // 512000
  p.hmic_ws = ws + 1556000;          // 512000
  int* idxbuf = (int*)(ws + 2068000);// 5120 ints
  p.idxA = idxbuf;
  p.idxB = idxbuf + NA*BATCH;
  p.WhhTmac = WhhTmac; p.WhhTmic = WhhTmic; p.WihTmic = WihTmic; p.WihTmac = WihTmac;

  p.ret   = (float*)d_out;
  p.goals = (float*)d_out + (size_t)(T_STEPS+1)*BATCH*YDIM;  // 327680

  prep_kernel<<<(1044000 + 255)/256, 256, 0, stream>>>(
      Whh_mac, Whh_mic, Wih_mic, Wih_mac, WhhTmac, WhhTmic, WihTmic, WihTmac);

  for (int t = 0; t < T_STEPS; ++t)
    step_kernel<<<NA*64, NT, 0, stream>>>(p, t);
}

// Round 2
// 9710.889 us; speedup vs baseline: 1.3035x; 1.3035x over previous
//
#include <hip/hip_runtime.h>

// MACRO_VRNN: 63-step scan, (agent, batch-chunk-of-8) x 320 wgs, one launch/step.
// R2: vectorized phases — thread = (4 output cols) x (K-quarter via lane quad),
// float4 weight loads, 4x fewer LDS act reads, quad shfl_xor reduction.

#define T_STEPS 63
#define BATCH   512
#define NA      5
#define YDIM    10
#define ZDIM    16
#define XDIM    2
#define HD      200
#define MDIM    90
#define HM      200
#define NB      8
#define NT      256

struct Params {
  const float *yin;
  const int   *mg;
  const float *Wdm1,*bdm1,*bdm2;
  const float *Wpr1,*bpr1,*Wpr2,*bpr2,*Wpm,*bpm,*Wps,*bps;
  const float *Wd1,*bd1,*Wd2,*bd2,*Wdx,*bdx,*Wds,*bds;
  const float *bih_mic,*bhh_mic,*bih_mac,*bhh_mac;
  const float *eps_g,*eps_z,*eps_x;
  const int   *burn;
  const float *WihTmic,*WhhTmic,*WihTmac,*WhhTmac,*Wdm2p;
  float *hmac_ws,*hmic_ws;
  int   *idxA,*idxB;
  float *ret,*goals;
};

__device__ __forceinline__ float sigm(float x){ return 1.f/(1.f+expf(-x)); }
__device__ __forceinline__ float softplusf(float x){ return log1pf(expf(-fabsf(x))) + fmaxf(x,0.f); }

// acc[c][j] += sum over this kseg's k of act[j*astride+k] * W[k*N + o + c]
template<int NBv>
__device__ __forceinline__ void mv4(const float* __restrict__ W, int N, int K,
                                    const float* __restrict__ act, int astride,
                                    int o, int kseg, float acc[4][NBv])
{
  const int Q = K >> 2;
  const int qpt = (Q + 3) >> 2;
  int q0 = kseg * qpt;
  int q1 = (Q < q0 + qpt) ? Q : (q0 + qpt);
  for (int q = q0; q < q1; ++q) {
    const float* wr = W + (size_t)(4*q)*N + o;
    const float4 w0 = *(const float4*)(wr);
    const float4 w1 = *(const float4*)(wr + N);
    const float4 w2 = *(const float4*)(wr + 2*N);
    const float4 w3 = *(const float4*)(wr + 3*N);
    #pragma unroll
    for (int j = 0; j < NBv; ++j) {
      const float4 av = *(const float4*)(act + j*astride + 4*q);
      acc[0][j] = fmaf(av.x, w0.x, acc[0][j]);
      acc[1][j] = fmaf(av.x, w0.y, acc[1][j]);
      acc[2][j] = fmaf(av.x, w0.z, acc[2][j]);
      acc[3][j] = fmaf(av.x, w0.w, acc[3][j]);
      acc[0][j] = fmaf(av.y, w1.x, acc[0][j]);
      acc[1][j] = fmaf(av.y, w1.y, acc[1][j]);
      acc[2][j] = fmaf(av.y, w1.z, acc[2][j]);
      acc[3][j] = fmaf(av.y, w1.w, acc[3][j]);
      acc[0][j] = fmaf(av.z, w2.x, acc[0][j]);
      acc[1][j] = fmaf(av.z, w2.y, acc[1][j]);
      acc[2][j] = fmaf(av.z, w2.z, acc[2][j]);
      acc[3][j] = fmaf(av.z, w2.w, acc[3][j]);
      acc[0][j] = fmaf(av.w, w3.x, acc[0][j]);
      acc[1][j] = fmaf(av.w, w3.y, acc[1][j]);
      acc[2][j] = fmaf(av.w, w3.z, acc[2][j]);
      acc[3][j] = fmaf(av.w, w3.w, acc[3][j]);
    }
  }
  if (kseg == 3) {            // K%4 tail
    for (int k = Q*4; k < K; ++k) {
      const float4 w = *(const float4*)(W + (size_t)k*N + o);
      #pragma unroll
      for (int j = 0; j < NBv; ++j) {
        const float a = act[j*astride + k];
        acc[0][j] = fmaf(a, w.x, acc[0][j]);
        acc[1][j] = fmaf(a, w.y, acc[1][j]);
        acc[2][j] = fmaf(a, w.z, acc[2][j]);
        acc[3][j] = fmaf(a, w.w, acc[3][j]);
      }
    }
  }
}

template<int NBv>
__device__ __forceinline__ void qreduce(float acc[4][NBv]) {
  #pragma unroll
  for (int c = 0; c < 4; ++c)
    #pragma unroll
    for (int j = 0; j < NBv; ++j) {
      float v = acc[c][j];
      v += __shfl_xor(v, 1);
      v += __shfl_xor(v, 2);
      acc[c][j] = v;
    }
}

__global__ void prep_kernel(const float* __restrict__ Whh_mac, const float* __restrict__ Whh_mic,
                            const float* __restrict__ Wih_mic, const float* __restrict__ Wih_mac,
                            const float* __restrict__ Wdm2,
                            float* __restrict__ WhhTmac, float* __restrict__ WhhTmic,
                            float* __restrict__ WihTmic, float* __restrict__ WihTmac,
                            float* __restrict__ Wdm2p)
{
  int i = blockIdx.x * 256 + threadIdx.x;
  if (i < 120000) {                     // (600,200)->(200,600)
    int k = i / 600, g = i % 600;
    WhhTmac[i] = Whh_mac[g*200 + k];
  } else if (i < 720000) {              // (A,600,200)->(A,200,600)
    int j = i - 120000;
    int a = j / 120000, r = j % 120000;
    int k = r / 600, g = r % 600;
    WhhTmic[j] = Whh_mic[a*120000 + g*200 + k];
  } else if (i < 774000) {              // (A,600,18)->(A,18,600)
    int j = i - 720000;
    int a = j / 10800, r = j % 10800;
    int k = r / 600, g = r % 600;
    WihTmic[j] = Wih_mic[a*10800 + g*18 + k];
  } else if (i < 1044000) {             // (600,450)->(450,600)
    int j = i - 774000;
    int k = j / 600, g = j % 600;
    WihTmac[j] = Wih_mac[g*450 + k];
  } else if (i < 1140000) {             // (A,200,90)->(A,200,96) pad
    int j = i - 1044000;
    int a = j / 19200, r = j % 19200;
    int k = r / 96, o = r % 96;
    Wdm2p[j] = (o < 90) ? Wdm2[(a*200 + k)*90 + o] : 0.f;
  }
}

__global__ __launch_bounds__(NT, 2) void step_kernel(Params p, int t)
{
  __shared__ __align__(16) float sY[NB][12];
  __shared__ __align__(16) float sHmac[NB][208];
  __shared__ __align__(16) float sHmic[NB][208];
  __shared__ __align__(16) float sGS[NB][608];
  __shared__ __align__(16) float sHn[NB][208];
  __shared__ __align__(16) float sB1[NB][208];
  __shared__ __align__(16) float sB2[NB][208];
  __shared__ __align__(16) float sLog[NB][96];
  __shared__ __align__(16) float sZ[NB][16];
  __shared__ __align__(16) float sXC[NB][20];
  __shared__ float sRedM[NB][2][8];
  __shared__ float sRedS[NB][2][8];
  __shared__ int   sIdxP[NA][NB];
  __shared__ int   sMid[NB];

  const int tid = threadIdx.x;
  const int bid = blockIdx.x;
  const int X = bid & 7, slot = bid >> 3;
  const int jj = X * 40 + slot;
  const int a  = jj >> 6;
  const int b0 = (jj & 63) * NB;
  const int burn = p.burn[0];
  const int* idxPrev = (t & 1) ? p.idxA : p.idxB;
  int*       idxCur  = (t & 1) ? p.idxB : p.idxA;

  const int og = tid >> 2;      // output quad group
  const int kseg = tid & 3;     // K quarter

  // ---- P0: load y, h_mac, h_mic, prev idx ----
  for (int u = tid; u < NB*YDIM; u += NT) {
    int j = u / YDIM, k = u % YDIM;
    float yv = (t == 0) ? p.yin[(b0+j)*YDIM + k]
                        : p.ret[(size_t)t*BATCH*YDIM + (b0+j)*YDIM + k];
    sY[j][k] = yv;
  }
  for (int u = tid; u < NB*HM; u += NT) {
    int j = u / HM, k = u % HM;
    size_t soff = ((size_t)a*BATCH + b0 + j)*HM + k;
    sHmac[j][k] = (t <= 1) ? 0.f : p.hmac_ws[soff];
    sHmic[j][k] = (t == 0) ? 0.f : p.hmic_ws[soff];
  }
  if (tid < NA*NB) {
    int a2 = tid / NB, j = tid % NB;
    sIdxP[a2][j] = (t == 0) ? -1 : idxPrev[a2*BATCH + b0 + j];
  }
  if (t == 0 && tid < NB*XDIM) {
    int j = tid >> 1, o = tid & 1;
    p.ret[(b0+j)*YDIM + a*XDIM + o] = p.yin[(b0+j)*YDIM + a*XDIM + o];
  }
  __syncthreads();

  // ---- P1: h_mac GRU (deferred from prev step), replicated per agent ----
  if (t > 0) {
    #pragma unroll 1
    for (int pass = 0; pass < 3; ++pass) {
      int g4 = og + pass*64;
      if (g4 < 150) {
        int g = g4*4;
        float aI[4][NB], aH[4][NB];
        #pragma unroll
        for (int c = 0; c < 4; ++c)
          #pragma unroll
          for (int j = 0; j < NB; ++j) { aI[c][j] = 0.f; aH[c][j] = 0.f; }
        for (int a2 = kseg; a2 < NA; a2 += 4) {
          #pragma unroll
          for (int j = 0; j < NB; ++j) {
            int r = sIdxP[a2][j];
            if (r >= 0) {
              const float4 w = *(const float4*)(p.WihTmac + (size_t)(a2*MDIM + r)*600 + g);
              aI[0][j] += w.x; aI[1][j] += w.y; aI[2][j] += w.z; aI[3][j] += w.w;
            }
          }
        }
        mv4<NB>(p.WhhTmac, 600, HM, &sHmac[0][0], 208, g, kseg, aH);
        qreduce<NB>(aI);
        qreduce<NB>(aH);
        const float4 bi = *(const float4*)(p.bih_mac + g);
        const float4 bh = *(const float4*)(p.bhh_mac + g);
        #pragma unroll
        for (int j = 0; j < NB; ++j) {
          if ((j >> 1) == kseg) {
            float i0 = aI[0][j]+bi.x, i1 = aI[1][j]+bi.y, i2 = aI[2][j]+bi.z, i3 = aI[3][j]+bi.w;
            float h0 = aH[0][j]+bh.x, h1 = aH[1][j]+bh.y, h2 = aH[2][j]+bh.z, h3 = aH[3][j]+bh.w;
            if (g < 400) {
              *(float4*)&sGS[j][g] = make_float4(i0+h0, i1+h1, i2+h2, i3+h3);
            } else {
              *(float4*)&sGS[j][g] = make_float4(i0, i1, i2, i3);
              *(float4*)&sHn[j][g-400] = make_float4(h0, h1, h2, h3);
            }
          }
        }
      }
    }
    __syncthreads();
    for (int u = tid; u < NB*HM; u += NT) {
      int j = u / HM, k = u % HM;
      float r  = sigm(sGS[j][k]);
      float zg = sigm(sGS[j][200+k]);
      float nh = (1.f - zg)*tanhf(sGS[j][400+k] + r*sHn[j][k]) + zg*sHmac[j][k];
      sHmac[j][k] = nh;
      p.hmac_ws[((size_t)a*BATCH + b0 + j)*HM + k] = nh;
    }
    __syncthreads();
  }

  // ---- P2: hdm = relu([y,hmac]@Wdm1); logits = hdm@Wdm2 ----
  if (og < 50) {
    int o = og*4;
    float acc[4][NB];
    #pragma unroll
    for (int c = 0; c < 4; ++c)
      #pragma unroll
      for (int j = 0; j < NB; ++j) acc[c][j] = 0.f;
    const float* W = p.Wdm1 + (size_t)a*(YDIM+HM)*HD;
    mv4<NB>(W, HD, YDIM, &sY[0][0], 12, o, kseg, acc);
    mv4<NB>(W + (size_t)YDIM*HD, HD, HM, &sHmac[0][0], 208, o, kseg, acc);
    qreduce<NB>(acc);
    const float4 bv = *(const float4*)(p.bdm1 + a*HD + o);
    #pragma unroll
    for (int j = 0; j < NB; ++j) {
      if ((j >> 1) == kseg) {
        *(float4*)&sB1[j][o] = make_float4(
          fmaxf(acc[0][j]+bv.x, 0.f), fmaxf(acc[1][j]+bv.y, 0.f),
          fmaxf(acc[2][j]+bv.z, 0.f), fmaxf(acc[3][j]+bv.w, 0.f));
      }
    }
  }
  __syncthreads();
  if (og < 24) {                       // logits via padded Wdm2p [200][96]
    int o = og*4;
    float acc[4][NB];
    #pragma unroll
    for (int c = 0; c < 4; ++c)
      #pragma unroll
      for (int j = 0; j < NB; ++j) acc[c][j] = 0.f;
    mv4<NB>(p.Wdm2p + (size_t)a*HD*96, 96, HD, &sB1[0][0], 208, o, kseg, acc);
    qreduce<NB>(acc);
    float b0v = (o+0 < MDIM) ? p.bdm2[a*MDIM + o+0] : 0.f;
    float b1v = (o+1 < MDIM) ? p.bdm2[a*MDIM + o+1] : 0.f;
    float b2v = (o+2 < MDIM) ? p.bdm2[a*MDIM + o+2] : 0.f;
    float b3v = (o+3 < MDIM) ? p.bdm2[a*MDIM + o+3] : 0.f;
    #pragma unroll
    for (int j = 0; j < NB; ++j) {
      if ((j >> 1) == kseg) {
        *(float4*)&sLog[j][o] = make_float4(acc[0][j]+b0v, acc[1][j]+b1v,
                                            acc[2][j]+b2v, acc[3][j]+b3v);
      }
    }
  }
  __syncthreads();
  for (int u = tid; u < NB*MDIM; u += NT) {
    int j = u / MDIM, cc = u % MDIM;
    sLog[j][cc] += p.eps_g[(((size_t)t*NA + a)*BATCH + b0 + j)*MDIM + cc];
  }
  __syncthreads();
  if (tid < NB) {
    int j = tid;
    float best = sLog[j][0]; int bi = 0;
    for (int cc = 1; cc < MDIM; ++cc) { float v = sLog[j][cc]; if (v > best) { best = v; bi = cc; } }
    int curr = p.mg[(size_t)t*BATCH*NA + a];
    bool sf = (curr == -1) || ((t >= burn) && (burn > 0));
    int mi = sf ? bi : ((b0 + j) == 0 ? curr : -1);
    sMid[j] = mi;
    float gv = (float)(mi < 0 ? 0 : mi);
    p.goals[(size_t)t*BATCH*NA + (b0+j)*NA + a] = gv;
    if (t == T_STEPS-1) p.goals[(size_t)T_STEPS*BATCH*NA + (b0+j)*NA + a] = gv;
    idxCur[a*BATCH + b0 + j] = mi;
  }
  __syncthreads();

  // ---- P3: hp = relu(relu([m,hmic]@Wpr1)@Wpr2); z = pm + softplus(ps)*eps ----
  if (og < 50) {
    int o = og*4;
    float acc[4][NB];
    #pragma unroll
    for (int c = 0; c < 4; ++c)
      #pragma unroll
      for (int j = 0; j < NB; ++j) acc[c][j] = 0.f;
    const float* W = p.Wpr1 + (size_t)a*(MDIM+HM)*HD;
    #pragma unroll
    for (int j = 0; j < NB; ++j) {
      if ((j >> 1) == kseg) {        // one-hot gather, one lane per j-pair
        int mi = sMid[j];
        if (mi >= 0) {
          const float4 w = *(const float4*)(W + (size_t)mi*HD + o);
          acc[0][j] += w.x; acc[1][j] += w.y; acc[2][j] += w.z; acc[3][j] += w.w;
        }
      }
    }
    mv4<NB>(W + (size_t)MDIM*HD, HD, HM, &sHmic[0][0], 208, o, kseg, acc);
    qreduce<NB>(acc);
    const float4 bv = *(const float4*)(p.bpr1 + a*HD + o);
    #pragma unroll
    for (int j = 0; j < NB; ++j) {
      if ((j >> 1) == kseg) {
        *(float4*)&sB2[j][o] = make_float4(
          fmaxf(acc[0][j]+bv.x, 0.f), fmaxf(acc[1][j]+bv.y, 0.f),
          fmaxf(acc[2][j]+bv.z, 0.f), fmaxf(acc[3][j]+bv.w, 0.f));
      }
    }
  }
  __syncthreads();
  if (og < 50) {
    int o = og*4;
    float acc[4][NB];
    #pragma unroll
    for (int c = 0; c < 4; ++c)
      #pragma unroll
      for (int j = 0; j < NB; ++j) acc[c][j] = 0.f;
    mv4<NB>(p.Wpr2 + (size_t)a*HD*HD, HD, HD, &sB2[0][0], 208, o, kseg, acc);
    qreduce<NB>(acc);
    const float4 bv = *(const float4*)(p.bpr2 + a*HD + o);
    #pragma unroll
    for (int j = 0; j < NB; ++j) {
      if ((j >> 1) == kseg) {
        *(float4*)&sB1[j][o] = make_float4(
          fmaxf(acc[0][j]+bv.x, 0.f), fmaxf(acc[1][j]+bv.y, 0.f),
          fmaxf(acc[2][j]+bv.z, 0.f), fmaxf(acc[3][j]+bv.w, 0.f));
      }
    }
  }
  __syncthreads();
  if (tid < NB*ZDIM) {
    int j = tid >> 4, o = tid & 15;
    float am = p.bpm[a*ZDIM + o], as = p.bps[a*ZDIM + o];
    const float* wm  = p.Wpm + (size_t)a*HD*ZDIM + o;
    const float* wsp = p.Wps + (size_t)a*HD*ZDIM + o;
    for (int k = 0; k < HD; ++k) {
      float h = sB1[j][k];
      am = fmaf(h, wm[(size_t)k*ZDIM], am);
      as = fmaf(h, wsp[(size_t)k*ZDIM], as);
    }
    float zv = am + softplusf(as) * p.eps_z[(((size_t)t*NA + a)*BATCH + b0 + j)*ZDIM + o];
    sZ[j][o] = zv;
    sXC[j][2+o] = zv;
  }
  __syncthreads();

  // ---- P4: hd = relu(relu([y,m,z,hmic]@Wd1)@Wd2); x = dx + softplus(ds)*eps ----
  if (og < 50) {
    int o = og*4;
    float acc[4][NB];
    #pragma unroll
    for (int c = 0; c < 4; ++c)
      #pragma unroll
      for (int j = 0; j < NB; ++j) acc[c][j] = 0.f;
    const float* W = p.Wd1 + (size_t)a*(YDIM+MDIM+ZDIM+HM)*HD;
    #pragma unroll
    for (int j = 0; j < NB; ++j) {
      if ((j >> 1) == kseg) {
        int mi = sMid[j];
        if (mi >= 0) {
          const float4 w = *(const float4*)(W + (size_t)(YDIM+mi)*HD + o);
          acc[0][j] += w.x; acc[1][j] += w.y; acc[2][j] += w.z; acc[3][j] += w.w;
        }
      }
    }
    mv4<NB>(W, HD, YDIM, &sY[0][0], 12, o, kseg, acc);
    mv4<NB>(W + (size_t)(YDIM+MDIM)*HD, HD, ZDIM, &sZ[0][0], 16, o, kseg, acc);
    mv4<NB>(W + (size_t)(YDIM+MDIM+ZDIM)*HD, HD, HM, &sHmic[0][0], 208, o, kseg, acc);
    qreduce<NB>(acc);
    const float4 bv = *(const float4*)(p.bd1 + a*HD + o);
    #pragma unroll
    for (int j = 0; j < NB; ++j) {
      if ((j >> 1) == kseg) {
        *(float4*)&sB2[j][o] = make_float4(
          fmaxf(acc[0][j]+bv.x, 0.f), fmaxf(acc[1][j]+bv.y, 0.f),
          fmaxf(acc[2][j]+bv.z, 0.f), fmaxf(acc[3][j]+bv.w, 0.f));
      }
    }
  }
  __syncthreads();
  if (og < 50) {
    int o = og*4;
    float acc[4][NB];
    #pragma unroll
    for (int c = 0; c < 4; ++c)
      #pragma unroll
      for (int j = 0; j < NB; ++j) acc[c][j] = 0.f;
    mv4<NB>(p.Wd2 + (size_t)a*HD*HD, HD, HD, &sB2[0][0], 208, o, kseg, acc);
    qreduce<NB>(acc);
    const float4 bv = *(const float4*)(p.bd2 + a*HD + o);
    #pragma unroll
    for (int j = 0; j < NB; ++j) {
      if ((j >> 1) == kseg) {
        *(float4*)&sB1[j][o] = make_float4(
          fmaxf(acc[0][j]+bv.x, 0.f), fmaxf(acc[1][j]+bv.y, 0.f),
          fmaxf(acc[2][j]+bv.z, 0.f), fmaxf(acc[3][j]+bv.w, 0.f));
      }
    }
  }
  __syncthreads();
  if (tid < 128) {
    int j = tid >> 4, o = (tid >> 3) & 1, seg = tid & 7;
    float am = 0.f, as = 0.f;
    const float* wx  = p.Wdx + (size_t)a*HD*XDIM + o;
    const float* wsd = p.Wds + (size_t)a*HD*XDIM + o;
    for (int k = seg*25; k < seg*25 + 25; ++k) {
      float h = sB1[j][k];
      am = fmaf(h, wx[(size_t)k*XDIM], am);
      as = fmaf(h, wsd[(size_t)k*XDIM], as);
    }
    sRedM[j][o][seg] = am; sRedS[j][o][seg] = as;
  }
  __syncthreads();
  if (tid < NB*XDIM) {
    int j = tid >> 1, o = tid & 1;
    float am = p.bdx[a*XDIM + o], as = p.bds[a*XDIM + o];
    for (int s2 = 0; s2 < 8; ++s2) { am += sRedM[j][o][s2]; as += sRedS[j][o][s2]; }
    float xs = am + softplusf(as) * p.eps_x[(((size_t)t*NA + a)*BATCH + b0 + j)*XDIM + o];
    float xt = p.yin[((size_t)(t+1))*BATCH*YDIM + (b0+j)*YDIM + a*XDIM + o];
    float xv = (t < burn) ? xt : xs;
    p.ret[((size_t)(t+1))*BATCH*YDIM + (b0+j)*YDIM + a*XDIM + o] = xv;
    sXC[j][o] = xv;
  }
  __syncthreads();

  // ---- P5: h_mic GRU ----
  #pragma unroll 1
  for (int pass = 0; pass < 3; ++pass) {
    int g4 = og + pass*64;
    if (g4 < 150) {
      int g = g4*4;
      float aI[4][NB], aH[4][NB];
      #pragma unroll
      for (int c = 0; c < 4; ++c)
        #pragma unroll
        for (int j = 0; j < NB; ++j) { aI[c][j] = 0.f; aH[c][j] = 0.f; }
      mv4<NB>(p.WihTmic + (size_t)a*18*600, 600, 18, &sXC[0][0], 20, g, kseg, aI);
      mv4<NB>(p.WhhTmic + (size_t)a*HM*600, 600, HM, &sHmic[0][0], 208, g, kseg, aH);
      qreduce<NB>(aI);
      qreduce<NB>(aH);
      const float4 bi = *(const float4*)(p.bih_mic + a*600 + g);
      const float4 bh = *(const float4*)(p.bhh_mic + a*600 + g);
      #pragma unroll
      for (int j = 0; j < NB; ++j) {
        if ((j >> 1) == kseg) {
          float i0 = aI[0][j]+bi.x, i1 = aI[1][j]+bi.y, i2 = aI[2][j]+bi.z, i3 = aI[3][j]+bi.w;
          float h0 = aH[0][j]+bh.x, h1 = aH[1][j]+bh.y, h2 = aH[2][j]+bh.z, h3 = aH[3][j]+bh.w;
          if (g < 400) {
            *(float4*)&sGS[j][g] = make_float4(i0+h0, i1+h1, i2+h2, i3+h3);
          } else {
            *(float4*)&sGS[j][g] = make_float4(i0, i1, i2, i3);
            *(float4*)&sHn[j][g-400] = make_float4(h0, h1, h2, h3);
          }
        }
      }
    }
  }
  __syncthreads();
  for (int u = tid; u < NB*HM; u += NT) {
    int j = u / HM, k = u % HM;
    float r  = sigm(sGS[j][k]);
    float zg = sigm(sGS[j][200+k]);
    float nh = (1.f - zg)*tanhf(sGS[j][400+k] + r*sHn[j][k]) + zg*sHmic[j][k];
    p.hmic_ws[((size_t)a*BATCH + b0 + j)*HM + k] = nh;
  }
}

extern "C" void kernel_launch(void* const* d_in, const int* in_sizes, int n_in,
                              void* d_out, int out_size, void* d_ws, size_t ws_size,
                              hipStream_t stream) {
  (void)in_sizes; (void)n_in; (void)out_size; (void)ws_size;
  Params p;
  p.yin   = (const float*)d_in[0];
  p.mg    = (const int*)  d_in[1];
  p.Wdm1  = (const float*)d_in[2];  p.bdm1 = (const float*)d_in[3];
  const float* Wdm2 = (const float*)d_in[4];
  p.bdm2  = (const float*)d_in[5];
  p.Wpr1  = (const float*)d_in[6];  p.bpr1 = (const float*)d_in[7];
  p.Wpr2  = (const float*)d_in[8];  p.bpr2 = (const float*)d_in[9];
  p.Wpm   = (const float*)d_in[10]; p.bpm  = (const float*)d_in[11];
  p.Wps   = (const float*)d_in[12]; p.bps  = (const float*)d_in[13];
  p.Wd1   = (const float*)d_in[14]; p.bd1  = (const float*)d_in[15];
  p.Wd2   = (const float*)d_in[16]; p.bd2  = (const float*)d_in[17];
  p.Wdx   = (const float*)d_in[18]; p.bdx  = (const float*)d_in[19];
  p.Wds   = (const float*)d_in[20]; p.bds  = (const float*)d_in[21];
  const float* Wih_mic = (const float*)d_in[22];
  const float* Whh_mic = (const float*)d_in[23];
  p.bih_mic = (const float*)d_in[24]; p.bhh_mic = (const float*)d_in[25];
  const float* Wih_mac = (const float*)d_in[26];
  const float* Whh_mac = (const float*)d_in[27];
  p.bih_mac = (const float*)d_in[28]; p.bhh_mac = (const float*)d_in[29];
  p.eps_g = (const float*)d_in[30];
  p.eps_z = (const float*)d_in[31];
  p.eps_x = (const float*)d_in[32];
  p.burn  = (const int*)  d_in[33];

  float* ws = (float*)d_ws;
  float* WhhTmac = ws;               // 120000
  float* WhhTmic = ws + 120000;      // 600000
  float* WihTmic = ws + 720000;      // 54000
  float* WihTmac = ws + 774000;      // 270000
  float* Wdm2p   = ws + 1044000;     // 96000
  p.hmac_ws = ws + 1140000;          // 512000
  p.hmic_ws = ws + 1652000;          // 512000
  int* idxbuf = (int*)(ws + 2164000);// 5120 ints
  p.idxA = idxbuf;
  p.idxB = idxbuf + NA*BATCH;
  p.WhhTmac = WhhTmac; p.WhhTmic = WhhTmic; p.WihTmic = WihTmic; p.WihTmac = WihTmac;
  p.Wdm2p = Wdm2p;

  p.ret   = (float*)d_out;
  p.goals = (float*)d_out + (size_t)(T_STEPS+1)*BATCH*YDIM;

  prep_kernel<<<(1140000 + 255)/256, 256, 0, stream>>>(
      Whh_mac, Whh_mic, Wih_mic, Wih_mac, Wdm2,
      WhhTmac, WhhTmic, WihTmic, WihTmac, Wdm2p);

  for (int t = 0; t < T_STEPS; ++t)
    step_kernel<<<NA*64, NT, 0, stream>>>(p, t);
}